// Round 1
// baseline (1266.042 us; speedup 1.0000x reference)
//
#include <hip/hip_runtime.h>
#include <stdint.h>

typedef unsigned int u32;
typedef unsigned long long u64;

#define NB 16
#define NA 16384
#define KD 128
#define NM 524288

// output offsets (floats)
#define OFF_Y    0
#define OFF_YHAT 16
#define OFF_SM   32
#define OFF_CLS  4128
#define OFF_LOC  4129
#define OFF_Q    4130
#define OFF_KEYS 6178
#define OFF_VALS 67115042
#define OFF_AGE  67639330

// ws offsets (bytes)
#define WS_SAMPLES 0        // 16*128 f32
#define WS_NUMPOS  8192     // 16 f32
#define WS_YMAX    8256     // 16 i32
#define WS_LOCSUM  8320     // 1 f32
#define WS_QUERY   8384     // 16*128 f32
#define WS_ROWLOSS 16576    // 16 f32
#define WS_YHATIDX 16640    // 16 i32
#define WS_RESULT  16768    // 16 i32
#define WS_HISTS   16832    // 16*640 u32
#define WS_THRESH  57792    // 16 f32
#define WS_CANDCNT 57856    // 16 i32
#define WS_HISTAGE 57920    // 8192 u32
#define WS_AGETH   90688    // 1 i32
#define WS_AGECNT  90692    // 1 i32
#define WS_AGECAND 90816    // 4096 int2
#define WS_CAND    123584   // 16*2048 int2
#define WS_SCORES  385728   // NM*16 f32 (transposed: scores[m*16+b])
#define WS_ZERO    123584

// ---------------- K1: samples[b][k] = sum_a pos * cls_preds ----------------
__global__ __launch_bounds__(256) void k_cls_sum(const float4* __restrict__ cls4,
                                                 const int* __restrict__ tgt,
                                                 float* __restrict__ samples) {
  int blk = blockIdx.x;
  int b = blk >> 5, chunk = blk & 31;          // 32 chunks of 512 anchors
  int tid = threadIdx.x;
  int kg = tid & 31, sub = tid >> 5;           // kg: float4 group (128 k), sub: 0..7
  float4 acc = make_float4(0.f, 0.f, 0.f, 0.f);
  int a0 = chunk * 512;
  for (int a = a0 + sub; a < a0 + 512; a += 8) {
    int t = tgt[b * NA + a];
    if (t > 0) {
      float4 v = cls4[((size_t)(b * NA + a)) * 32 + kg];
      acc.x += v.x; acc.y += v.y; acc.z += v.z; acc.w += v.w;
    }
  }
  __shared__ float4 red[256];
  red[tid] = acc;
  __syncthreads();
  if (tid < 32) {
    float4 s = red[tid];
    for (int r = 1; r < 8; ++r) {
      float4 v = red[r * 32 + tid];
      s.x += v.x; s.y += v.y; s.z += v.z; s.w += v.w;
    }
    atomicAdd(&samples[b * KD + kg * 4 + 0], s.x);
    atomicAdd(&samples[b * KD + kg * 4 + 1], s.y);
    atomicAdd(&samples[b * KD + kg * 4 + 2], s.z);
    atomicAdd(&samples[b * KD + kg * 4 + 3], s.w);
  }
}

// ---------------- K2: num_pos, loc_loss partial, y = max target ----------------
__global__ __launch_bounds__(256) void k_loc(const float4* __restrict__ lp, const float4* __restrict__ lt,
                                             const int* __restrict__ tgt, float* __restrict__ numpos,
                                             int* __restrict__ ymax, float* __restrict__ locsum) {
  int i = blockIdx.x * 256 + threadIdx.x;
  int b = i >> 14;
  int t = tgt[i];
  float cnt = (t > 0) ? 1.f : 0.f;
  float sl = 0.f;
  if (t > 0) {
    float4 p = lp[i], q = lt[i];
    float d0 = p.x - q.x, d1 = p.y - q.y, d2 = p.z - q.z, d3 = p.w - q.w;
    float a0 = fabsf(d0), a1 = fabsf(d1), a2 = fabsf(d2), a3 = fabsf(d3);
    sl = ((a0 < 1.f) ? 0.5f * d0 * d0 : a0 - 0.5f)
       + ((a1 < 1.f) ? 0.5f * d1 * d1 : a1 - 0.5f)
       + ((a2 < 1.f) ? 0.5f * d2 * d2 : a2 - 0.5f)
       + ((a3 < 1.f) ? 0.5f * d3 * d3 : a3 - 0.5f);
  }
  for (int o = 32; o > 0; o >>= 1) {
    sl += __shfl_down(sl, o);
    cnt += __shfl_down(cnt, o);
    t = max(t, __shfl_down(t, o));
  }
  __shared__ float s_sl[4], s_cnt[4];
  __shared__ int s_t[4];
  int lane = threadIdx.x & 63, w = threadIdx.x >> 6;
  if (lane == 0) { s_sl[w] = sl; s_cnt[w] = cnt; s_t[w] = t; }
  __syncthreads();
  if (threadIdx.x == 0) {
    float SL = s_sl[0] + s_sl[1] + s_sl[2] + s_sl[3];
    float CN = s_cnt[0] + s_cnt[1] + s_cnt[2] + s_cnt[3];
    int T = max(max(s_t[0], s_t[1]), max(s_t[2], s_t[3]));
    atomicAdd(&numpos[b], CN);
    atomicAdd(locsum, SL);
    atomicMax(&ymax[b], T);
  }
}

// ---------------- K3: query = l2norm(samples/num_pos); y, loc_loss out ----------------
__global__ __launch_bounds__(128) void k_query(const float* __restrict__ samples, const float* __restrict__ numpos,
                                               const int* __restrict__ ymax, const float* __restrict__ locsum,
                                               float* __restrict__ qws, float* __restrict__ outf) {
  int tid = threadIdx.x;
  __shared__ float partial[2];
  for (int b = 0; b < NB; ++b) {
    float np_ = numpos[b];
    float v = samples[b * KD + tid] / np_;
    float sq = v * v;
    for (int o = 32; o > 0; o >>= 1) sq += __shfl_down(sq, o);
    if ((tid & 63) == 0) partial[tid >> 6] = sq;
    __syncthreads();
    float nrm = sqrtf(partial[0] + partial[1]);
    float q = v / fmaxf(nrm, 1e-12f);
    qws[b * KD + tid] = q;
    outf[OFF_Q + b * KD + tid] = q;
    __syncthreads();
  }
  if (tid < 16) outf[OFF_Y + tid] = (float)ymax[tid];
  if (tid == 0) {
    float tot = 0.f;
    for (int b = 0; b < NB; ++b) tot += numpos[b];
    outf[OFF_LOC] = locsum[0] / tot;
  }
}

// ---------------- K4: scores = query @ keys.T ; copy keys/values/age to out ----------------
// Line-granular decomposition: 8 lanes per key row, lane p owns float4s {p, p+8, p+16, p+24}.
// Every global load/store instruction covers full 128-B lines -> no write-allocate, no
// partial-dirty-line churn. 2 rows per thread amortize the LDS q broadcasts.
__device__ __forceinline__ float2 reduce_scatter8(const float* a, int p) {
  // 3-level xor butterfly reduce-scatter over the 8 lanes of a row group.
  // Lane p ends holding the full row-sums for b = 2p and 2p+1. All indices static.
  float t8[8];
#pragma unroll
  for (int b = 0; b < 8; ++b) {
    float keep = (p & 4) ? a[b + 8] : a[b];
    float send = (p & 4) ? a[b] : a[b + 8];
    t8[b] = keep + __shfl_xor(send, 4);
  }
  float t4[4];
#pragma unroll
  for (int b = 0; b < 4; ++b) {
    float keep = (p & 2) ? t8[b + 4] : t8[b];
    float send = (p & 2) ? t8[b] : t8[b + 4];
    t4[b] = keep + __shfl_xor(send, 2);
  }
  float t2[2];
#pragma unroll
  for (int b = 0; b < 2; ++b) {
    float keep = (p & 1) ? t4[b + 2] : t4[b];
    float send = (p & 1) ? t4[b] : t4[b + 2];
    t2[b] = keep + __shfl_xor(send, 1);
  }
  return make_float2(t2[0], t2[1]);
}

__global__ __launch_bounds__(256) void k_scores(const float4* __restrict__ keys4, const float4* __restrict__ q4,
                                                const int* __restrict__ vals, const float* __restrict__ age,
                                                float* __restrict__ outf, float* __restrict__ scores) {
  __shared__ float4 ql[512];
  int tid = threadIdx.x;
  for (int i = tid; i < 512; i += 256) ql[i] = q4[i];
  // vals/age copy: one row per thread, coalesced 4-B stores
  int mc = blockIdx.x * 256 + tid;
  outf[OFF_VALS + mc] = (float)vals[mc];
  outf[OFF_AGE + mc] = age[mc] + 1.f;
  __syncthreads();

  int p = tid & 7, r = tid >> 3;               // 8 lanes per row, 32 rows per block-pass
  float2* ok2 = (float2*)(outf + OFF_KEYS);    // dest only 8-B aligned
  float2* sc2 = (float2*)scores;
  int m_base = blockIdx.x * 256;

#pragma unroll 1
  for (int t = 0; t < 4; ++t) {                // 4 passes x 64 rows = 256 rows/block
    int row0 = m_base + t * 64 + r;
    int row1 = row0 + 32;
    float4 kv0[4], kv1[4];
#pragma unroll
    for (int u = 0; u < 4; ++u) {
      kv0[u] = keys4[(size_t)row0 * 32 + u * 8 + p];   // 8 full lines / instr
      kv1[u] = keys4[(size_t)row1 * 32 + u * 8 + p];
    }
    // coalesced copy-out: pair of float2 stores covers each 128-B line back-to-back
#pragma unroll
    for (int u = 0; u < 4; ++u) {
      size_t g0 = (size_t)row0 * 32 + u * 8 + p;
      size_t g1 = (size_t)row1 * 32 + u * 8 + p;
      ok2[2 * g0]     = make_float2(kv0[u].x, kv0[u].y);
      ok2[2 * g0 + 1] = make_float2(kv0[u].z, kv0[u].w);
      ok2[2 * g1]     = make_float2(kv1[u].x, kv1[u].y);
      ok2[2 * g1 + 1] = make_float2(kv1[u].z, kv1[u].w);
    }
    float acc0[16], acc1[16];
#pragma unroll
    for (int b = 0; b < 16; ++b) { acc0[b] = 0.f; acc1[b] = 0.f; }
#pragma unroll
    for (int u = 0; u < 4; ++u) {
#pragma unroll
      for (int b = 0; b < 16; ++b) {
        float4 q = ql[b * 32 + u * 8 + p];     // 8 addrs x 8-lane broadcast: conflict-free
        acc0[b] += kv0[u].x * q.x + kv0[u].y * q.y + kv0[u].z * q.z + kv0[u].w * q.w;
        acc1[b] += kv1[u].x * q.x + kv1[u].y * q.y + kv1[u].z * q.z + kv1[u].w * q.w;
      }
    }
    // lane p writes scores b=2p,2p+1: wave covers 512 contiguous bytes per store
    sc2[(size_t)row0 * 8 + p] = reduce_scatter8(acc0, p);
    sc2[(size_t)row1 * 8 + p] = reduce_scatter8(acc1, p);
  }
}

// ---------------- K5: per-row histogram of scores >= 0.0625 (bin = float hi-16 bits) ----------------
__global__ __launch_bounds__(256) void k_hist(const float* __restrict__ scores, u32* __restrict__ ghist) {
  __shared__ u32 h[16 * 640];
  int tid = threadIdx.x;
  for (int i = tid; i < 16 * 640; i += 256) h[i] = 0;
  __syncthreads();
  int m0 = blockIdx.x * 1024;
  for (int s = 0; s < 4; ++s) {
    int m = m0 + s * 256 + tid;
    const float4* sc = (const float4*)(scores + (size_t)m * 16);
#pragma unroll
    for (int g = 0; g < 4; ++g) {
      float4 v = sc[g];
      float fv[4] = {v.x, v.y, v.z, v.w};
#pragma unroll
      for (int c = 0; c < 4; ++c) {
        float f = fv[c];
        if (f >= 0.0625f) {
          u32 u = __float_as_uint(f);
          int bin = (int)(u >> 16) - 0x3D80;
          if (bin > 639) bin = 639;
          atomicAdd(&h[(g * 4 + c) * 640 + bin], 1u);
        }
      }
    }
  }
  __syncthreads();
  for (int i = tid; i < 16 * 640; i += 256) {
    u32 v = h[i];
    if (v) atomicAdd(&ghist[i], v);
  }
}

// ---------------- K6: per-row threshold value from histogram ----------------
__global__ void k_scan(const u32* __restrict__ ghist, float* __restrict__ thresh) {
  int b = threadIdx.x;
  if (b < 16) {
    u32 cum = 0;
    int T = 0;
    for (int i = 639; i >= 0; --i) {
      cum += ghist[b * 640 + i];
      if (cum >= 256) { T = i; break; }
    }
    thresh[b] = __uint_as_float(((u32)(T + 0x3D80)) << 16);
  }
}

// ---------------- K7: gather candidates >= threshold ----------------
__global__ __launch_bounds__(256) void k_gather(const float* __restrict__ scores, const float* __restrict__ thresh,
                                                int* __restrict__ cnt, int2* __restrict__ cand) {
  __shared__ float th[16];
  int tid = threadIdx.x;
  if (tid < 16) th[tid] = thresh[tid];
  __syncthreads();
  int m0 = blockIdx.x * 1024;
  for (int s = 0; s < 4; ++s) {
    int m = m0 + s * 256 + tid;
    const float4* sc = (const float4*)(scores + (size_t)m * 16);
#pragma unroll
    for (int g = 0; g < 4; ++g) {
      float4 v = sc[g];
      float fv[4] = {v.x, v.y, v.z, v.w};
#pragma unroll
      for (int c = 0; c < 4; ++c) {
        int b = g * 4 + c;
        float f = fv[c];
        if (f >= th[b]) {
          int p = atomicAdd(&cnt[b], 1);
          if (p < 2048) cand[b * 2048 + p] = make_int2(__float_as_int(f), m);
        }
      }
    }
  }
}

// ---------------- K8: per-row exact top-256 (bitonic), softmax, margin loss ----------------
__global__ __launch_bounds__(256) void k_topk(const int2* __restrict__ cand, const int* __restrict__ cnt,
                                              const int* __restrict__ vals, const int* __restrict__ ymax,
                                              float* __restrict__ outf, float* __restrict__ rowloss,
                                              int* __restrict__ yhatidx, int* __restrict__ result) {
  int b = blockIdx.x, tid = threadIdx.x;
  __shared__ u64 sk[2048];
  __shared__ float rb[256];
  __shared__ int sidx0;
  int nc = cnt[b];
  if (nc > 2048) nc = 2048;
  for (int i = tid; i < 2048; i += 256) {
    u64 key = 0;
    if (i < nc) {
      int2 c = cand[b * 2048 + i];
      key = ((u64)(u32)c.x << 32) | (u32)(~(u32)c.y);  // score desc, idx asc
    }
    sk[i] = key;
  }
  __syncthreads();
  for (int k2 = 2; k2 <= 2048; k2 <<= 1)
    for (int j2 = k2 >> 1; j2 > 0; j2 >>= 1) {
      for (int i = tid; i < 2048; i += 256) {
        int ix = i ^ j2;
        if (ix > i) {
          u64 x = sk[i], y = sk[ix];
          bool sw = ((i & k2) == 0) ? (x < y) : (x > y);  // descending
          if (sw) { sk[i] = y; sk[ix] = x; }
        }
      }
      __syncthreads();
    }
  int y = ymax[b];
  u64 kk = sk[tid];
  float c_ = __uint_as_float((u32)(kk >> 32));
  int id = (int)(~(u32)(kk & 0xFFFFFFFFull));
  id = min(max(id, 0), NM - 1);
  int vv = vals[id];
  int mk = (vv == y) ? 1 : 0;
  if (tid == 0) sidx0 = id;
  float mx = __uint_as_float((u32)(sk[0] >> 32));
  float e = expf(c_ - mx);
  rb[tid] = e; __syncthreads();
  for (int o = 128; o > 0; o >>= 1) { if (tid < o) rb[tid] += rb[tid + o]; __syncthreads(); }
  float esum = rb[0]; __syncthreads();
  outf[OFF_SM + b * 256 + tid] = e / esum;
  rb[tid] = c_ * (float)mk; __syncthreads();
  for (int o = 128; o > 0; o >>= 1) { if (tid < o) rb[tid] = fmaxf(rb[tid], rb[tid + o]); __syncthreads(); }
  float pmax = rb[0]; __syncthreads();
  rb[tid] = c_ * (float)(1 - mk); __syncthreads();
  for (int o = 128; o > 0; o >>= 1) { if (tid < o) rb[tid] = fmaxf(rb[tid], rb[tid + o]); __syncthreads(); }
  float nmax = rb[0]; __syncthreads();
  rb[tid] = (float)mk; __syncthreads();
  for (int o = 128; o > 0; o >>= 1) { if (tid < o) rb[tid] += rb[tid + o]; __syncthreads(); }
  float msum = rb[0];
  if (tid == 0) {
    float pos = (msum > 0.f) ? pmax : 0.f;
    rowloss[b] = fmaxf(nmax - pos + 0.1f, 0.f);
    int yh = vals[sidx0];
    yhatidx[b] = sidx0;
    result[b] = (yh == y) ? 1 : 0;
    outf[OFF_YHAT + b] = (float)yh;
  }
}

// ---------------- K9: correct-prediction key refresh (serial b, last-wins) + cls_loss ----------------
__global__ __launch_bounds__(128) void k_corr(const float* __restrict__ keys, const float* __restrict__ qws,
                                              const float* __restrict__ rowloss, const int* __restrict__ yhatidx,
                                              const int* __restrict__ result, float* __restrict__ outf) {
  int tid = threadIdx.x;
  __shared__ float partial[2];
  if (tid == 0) {
    float sum = 0.f;
    for (int b = 0; b < NB; ++b) sum += rowloss[b];
    outf[OFF_CLS] = sum * (1.f / 16.f);
  }
  for (int b = 0; b < NB; ++b) {
    if (result[b]) {
      int dest = yhatidx[b];
      float v = keys[(size_t)dest * KD + tid] + qws[b * KD + tid];
      float sq = v * v;
      for (int o = 32; o > 0; o >>= 1) sq += __shfl_down(sq, o);
      if ((tid & 63) == 0) partial[tid >> 6] = sq;
      __syncthreads();
      float nrm = sqrtf(partial[0] + partial[1]);
      outf[OFF_KEYS + (size_t)dest * KD + tid] = v / fmaxf(nrm, 1e-12f);
      if (tid == 0) outf[OFF_AGE + dest] = 0.f;
    }
    __syncthreads();
  }
}

__device__ __forceinline__ int age_bin(float an) {
  // deterministic (no-contract) binning, identical in hist and gather kernels
  float x = __fmul_rn(__fadd_rn(an, 8.f), 8192.f / 120.f);
  int bin = (int)x;
  return min(max(bin, 0), 8191);
}

// ---------------- K10a: histogram of age_noisy ----------------
__global__ __launch_bounds__(256) void k_hage(const float* __restrict__ oage, const float* __restrict__ noise,
                                              u32* __restrict__ hist) {
  __shared__ u32 h[8192];
  int tid = threadIdx.x;
  for (int i = tid; i < 8192; i += 256) h[i] = 0;
  __syncthreads();
  int m0 = blockIdx.x * 4096;
  for (int s = 0; s < 16; ++s) {
    int m = m0 + s * 256 + tid;
    float an = oage[m] + (noise[m] * 2.f - 1.f) * 8.f;
    atomicAdd(&h[age_bin(an)], 1u);
  }
  __syncthreads();
  for (int i = tid; i < 8192; i += 256) {
    u32 v = h[i];
    if (v) atomicAdd(&hist[i], v);
  }
}

// ---------------- K10b: threshold bin for top-16 ----------------
__global__ void k_scan_age(const u32* __restrict__ hist, int* __restrict__ T) {
  if (threadIdx.x == 0) {
    u32 cum = 0;
    int t = 0;
    for (int i = 8191; i >= 0; --i) {
      cum += hist[i];
      if (cum >= 16) { t = i; break; }
    }
    *T = t;
  }
}

// ---------------- K10c: gather age candidates ----------------
__global__ __launch_bounds__(256) void k_gage(const float* __restrict__ oage, const float* __restrict__ noise,
                                              const int* __restrict__ T, int* __restrict__ cnt,
                                              int2* __restrict__ cand) {
  int tb = *T;
  int tid = threadIdx.x;
  int m0 = blockIdx.x * 1024;
  for (int s = 0; s < 4; ++s) {
    int m = m0 + s * 256 + tid;
    float an = oage[m] + (noise[m] * 2.f - 1.f) * 8.f;
    if (age_bin(an) >= tb) {
      int p = atomicAdd(cnt, 1);
      if (p < 4096) {
        u32 u = __float_as_uint(an);
        u = (u & 0x80000000u) ? ~u : (u | 0x80000000u);  // order-preserving flip
        cand[p] = make_int2((int)u, m);
      }
    }
  }
}

// ---------------- K11: oldest top-16, incorrect-prediction inserts ----------------
__global__ __launch_bounds__(256) void k_inc(const int* __restrict__ cnt, const int2* __restrict__ cand,
                                             const float* __restrict__ qws, const int* __restrict__ ymax,
                                             const int* __restrict__ result, float* __restrict__ outf) {
  __shared__ u64 sk[2048];
  __shared__ int oldest[16];
  __shared__ int dest[16];
  int tid = threadIdx.x;
  int nc = *cnt;
  if (nc > 2048) nc = 2048;
  for (int i = tid; i < 2048; i += 256) {
    u64 key = 0;
    if (i < nc) {
      int2 c = cand[i];
      key = ((u64)(u32)c.x << 32) | (u32)(~(u32)c.y);
    }
    sk[i] = key;
  }
  __syncthreads();
  for (int k2 = 2; k2 <= 2048; k2 <<= 1)
    for (int j2 = k2 >> 1; j2 > 0; j2 >>= 1) {
      for (int i = tid; i < 2048; i += 256) {
        int ix = i ^ j2;
        if (ix > i) {
          u64 x = sk[i], y = sk[ix];
          bool sw = ((i & k2) == 0) ? (x < y) : (x > y);
          if (sw) { sk[i] = y; sk[ix] = x; }
        }
      }
      __syncthreads();
    }
  if (tid < 16) {
    int id = (int)(~(u32)(sk[tid] & 0xFFFFFFFFull));
    oldest[tid] = min(max(id, 0), NM - 1);
  }
  __syncthreads();
  if (tid == 0) {
    int r = 0;
    for (int b = 0; b < NB; ++b) {
      if (!result[b]) { dest[b] = oldest[min(r, 15)]; r++; }
      else dest[b] = -1;
    }
  }
  __syncthreads();
  for (int b = 0; b < NB; ++b) {
    int d = dest[b];
    if (d >= 0) {
      if (tid < KD) outf[OFF_KEYS + (size_t)d * KD + tid] = qws[b * KD + tid];
      if (tid == 0) {
        outf[OFF_VALS + d] = (float)ymax[b];
        outf[OFF_AGE + d] = 0.f;
      }
    }
  }
}

extern "C" void kernel_launch(void* const* d_in, const int* in_sizes, int n_in,
                              void* d_out, int out_size, void* d_ws, size_t ws_size,
                              hipStream_t stream) {
  const float4* lp   = (const float4*)d_in[0];
  const float4* cls4 = (const float4*)d_in[1];
  const float4* lt   = (const float4*)d_in[2];
  const int* tgt     = (const int*)d_in[3];
  const float* keys  = (const float*)d_in[4];
  const int* vals    = (const int*)d_in[5];
  const float* age   = (const float*)d_in[6];
  const float* noise = (const float*)d_in[7];
  float* outf = (float*)d_out;
  char* ws = (char*)d_ws;

  hipMemsetAsync(ws, 0, WS_ZERO, stream);
  k_cls_sum<<<512, 256, 0, stream>>>(cls4, tgt, (float*)(ws + WS_SAMPLES));
  k_loc<<<1024, 256, 0, stream>>>(lp, lt, tgt, (float*)(ws + WS_NUMPOS),
                                  (int*)(ws + WS_YMAX), (float*)(ws + WS_LOCSUM));
  k_query<<<1, 128, 0, stream>>>((const float*)(ws + WS_SAMPLES), (const float*)(ws + WS_NUMPOS),
                                 (const int*)(ws + WS_YMAX), (const float*)(ws + WS_LOCSUM),
                                 (float*)(ws + WS_QUERY), outf);
  k_scores<<<2048, 256, 0, stream>>>((const float4*)keys, (const float4*)(ws + WS_QUERY),
                                     vals, age, outf, (float*)(ws + WS_SCORES));
  k_hist<<<512, 256, 0, stream>>>((const float*)(ws + WS_SCORES), (u32*)(ws + WS_HISTS));
  k_scan<<<1, 64, 0, stream>>>((const u32*)(ws + WS_HISTS), (float*)(ws + WS_THRESH));
  k_gather<<<512, 256, 0, stream>>>((const float*)(ws + WS_SCORES), (const float*)(ws + WS_THRESH),
                                    (int*)(ws + WS_CANDCNT), (int2*)(ws + WS_CAND));
  k_topk<<<16, 256, 0, stream>>>((const int2*)(ws + WS_CAND), (const int*)(ws + WS_CANDCNT),
                                 vals, (const int*)(ws + WS_YMAX), outf, (float*)(ws + WS_ROWLOSS),
                                 (int*)(ws + WS_YHATIDX), (int*)(ws + WS_RESULT));
  k_corr<<<1, 128, 0, stream>>>(keys, (const float*)(ws + WS_QUERY), (const float*)(ws + WS_ROWLOSS),
                                (const int*)(ws + WS_YHATIDX), (const int*)(ws + WS_RESULT), outf);
  k_hage<<<128, 256, 0, stream>>>(outf + OFF_AGE, noise, (u32*)(ws + WS_HISTAGE));
  k_scan_age<<<1, 64, 0, stream>>>((const u32*)(ws + WS_HISTAGE), (int*)(ws + WS_AGETH));
  k_gage<<<512, 256, 0, stream>>>(outf + OFF_AGE, noise, (const int*)(ws + WS_AGETH),
                                  (int*)(ws + WS_AGECNT), (int2*)(ws + WS_AGECAND));
  k_inc<<<1, 256, 0, stream>>>((const int*)(ws + WS_AGECNT), (const int2*)(ws + WS_AGECAND),
                               (const float*)(ws + WS_QUERY), (const int*)(ws + WS_YMAX),
                               (const int*)(ws + WS_RESULT), outf);
}

// Round 2
// 877.133 us; speedup vs baseline: 1.4434x; 1.4434x over previous
//
#include <hip/hip_runtime.h>
#include <stdint.h>

typedef unsigned int u32;
typedef unsigned long long u64;

#define NB 16
#define NA 16384
#define KD 128
#define NM 524288

// output offsets (floats)
#define OFF_Y    0
#define OFF_YHAT 16
#define OFF_SM   32
#define OFF_CLS  4128
#define OFF_LOC  4129
#define OFF_Q    4130
#define OFF_KEYS 6178
#define OFF_VALS 67115042
#define OFF_AGE  67639330

// ws offsets (bytes)
#define WS_SAMPLES 0        // 16*128 f32
#define WS_NUMPOS  8192     // 16 f32
#define WS_YMAX    8256     // 16 i32
#define WS_LOCSUM  8320     // 1 f32
#define WS_QUERY   8384     // 16*128 f32
#define WS_ROWLOSS 16576    // 16 f32
#define WS_YHATIDX 16640    // 16 i32
#define WS_RESULT  16768    // 16 i32
#define WS_HISTS   16832    // 16*640 u32
#define WS_THRESH  57792    // 16 f32
#define WS_CANDCNT 57856    // 16 i32
#define WS_HISTAGE 57920    // 8192 u32
#define WS_AGETH   90688    // 1 i32
#define WS_AGECNT  90692    // 1 i32
#define WS_AGECAND 90816    // 4096 int2
#define WS_CAND    123584   // 16*2048 int2
#define WS_SCORES  385728   // NM*16 f32 (transposed: scores[m*16+b])
#define WS_ZERO    123584

// ---------------- K1: samples[b][k] = sum_a pos * cls_preds ----------------
__global__ __launch_bounds__(256) void k_cls_sum(const float4* __restrict__ cls4,
                                                 const int* __restrict__ tgt,
                                                 float* __restrict__ samples) {
  int blk = blockIdx.x;
  int b = blk >> 5, chunk = blk & 31;          // 32 chunks of 512 anchors
  int tid = threadIdx.x;
  int kg = tid & 31, sub = tid >> 5;           // kg: float4 group (128 k), sub: 0..7
  float4 acc = make_float4(0.f, 0.f, 0.f, 0.f);
  int a0 = chunk * 512;
  for (int a = a0 + sub; a < a0 + 512; a += 8) {
    int t = tgt[b * NA + a];
    if (t > 0) {
      float4 v = cls4[((size_t)(b * NA + a)) * 32 + kg];
      acc.x += v.x; acc.y += v.y; acc.z += v.z; acc.w += v.w;
    }
  }
  __shared__ float4 red[256];
  red[tid] = acc;
  __syncthreads();
  if (tid < 32) {
    float4 s = red[tid];
    for (int r = 1; r < 8; ++r) {
      float4 v = red[r * 32 + tid];
      s.x += v.x; s.y += v.y; s.z += v.z; s.w += v.w;
    }
    atomicAdd(&samples[b * KD + kg * 4 + 0], s.x);
    atomicAdd(&samples[b * KD + kg * 4 + 1], s.y);
    atomicAdd(&samples[b * KD + kg * 4 + 2], s.z);
    atomicAdd(&samples[b * KD + kg * 4 + 3], s.w);
  }
}

// ---------------- K2: num_pos, loc_loss partial, y = max target ----------------
__global__ __launch_bounds__(256) void k_loc(const float4* __restrict__ lp, const float4* __restrict__ lt,
                                             const int* __restrict__ tgt, float* __restrict__ numpos,
                                             int* __restrict__ ymax, float* __restrict__ locsum) {
  int i = blockIdx.x * 256 + threadIdx.x;
  int b = i >> 14;
  int t = tgt[i];
  float cnt = (t > 0) ? 1.f : 0.f;
  float sl = 0.f;
  if (t > 0) {
    float4 p = lp[i], q = lt[i];
    float d0 = p.x - q.x, d1 = p.y - q.y, d2 = p.z - q.z, d3 = p.w - q.w;
    float a0 = fabsf(d0), a1 = fabsf(d1), a2 = fabsf(d2), a3 = fabsf(d3);
    sl = ((a0 < 1.f) ? 0.5f * d0 * d0 : a0 - 0.5f)
       + ((a1 < 1.f) ? 0.5f * d1 * d1 : a1 - 0.5f)
       + ((a2 < 1.f) ? 0.5f * d2 * d2 : a2 - 0.5f)
       + ((a3 < 1.f) ? 0.5f * d3 * d3 : a3 - 0.5f);
  }
  for (int o = 32; o > 0; o >>= 1) {
    sl += __shfl_down(sl, o);
    cnt += __shfl_down(cnt, o);
    t = max(t, __shfl_down(t, o));
  }
  __shared__ float s_sl[4], s_cnt[4];
  __shared__ int s_t[4];
  int lane = threadIdx.x & 63, w = threadIdx.x >> 6;
  if (lane == 0) { s_sl[w] = sl; s_cnt[w] = cnt; s_t[w] = t; }
  __syncthreads();
  if (threadIdx.x == 0) {
    float SL = s_sl[0] + s_sl[1] + s_sl[2] + s_sl[3];
    float CN = s_cnt[0] + s_cnt[1] + s_cnt[2] + s_cnt[3];
    int T = max(max(s_t[0], s_t[1]), max(s_t[2], s_t[3]));
    atomicAdd(&numpos[b], CN);
    atomicAdd(locsum, SL);
    atomicMax(&ymax[b], T);
  }
}

// ---------------- K3: query = l2norm(samples/num_pos); y, loc_loss out ----------------
__global__ __launch_bounds__(128) void k_query(const float* __restrict__ samples, const float* __restrict__ numpos,
                                               const int* __restrict__ ymax, const float* __restrict__ locsum,
                                               float* __restrict__ qws, float* __restrict__ outf) {
  int tid = threadIdx.x;
  __shared__ float partial[2];
  for (int b = 0; b < NB; ++b) {
    float np_ = numpos[b];
    float v = samples[b * KD + tid] / np_;
    float sq = v * v;
    for (int o = 32; o > 0; o >>= 1) sq += __shfl_down(sq, o);
    if ((tid & 63) == 0) partial[tid >> 6] = sq;
    __syncthreads();
    float nrm = sqrtf(partial[0] + partial[1]);
    float q = v / fmaxf(nrm, 1e-12f);
    qws[b * KD + tid] = q;
    outf[OFF_Q + b * KD + tid] = q;
    __syncthreads();
  }
  if (tid < 16) outf[OFF_Y + tid] = (float)ymax[tid];
  if (tid == 0) {
    float tot = 0.f;
    for (int b = 0; b < NB; ++b) tot += numpos[b];
    outf[OFF_LOC] = locsum[0] / tot;
  }
}

// ---------------- K4: scores = query @ keys.T ; copy keys/values/age to out ----------------
// 8 lanes per key row (lane p owns float4s {p, p+8, p+16, p+24}) -> every global LOAD
// instruction covers 8 full 128-B lines. 1 row/thread keeps VGPR ~70 (occupancy).
// Copy-out goes through a 16-KB LDS tile so stores are 16-B-aligned float4 on the
// shifted grid (OFF_KEYS+2): each store instruction = 1024 contiguous fully-dirty bytes.
__device__ __forceinline__ float2 reduce_scatter8(const float* a, int p) {
  // 3-level xor butterfly reduce-scatter over the 8 lanes of a row group.
  // Lane p ends holding the full row-sums for b = 2p and 2p+1. All indices static.
  float t8[8];
#pragma unroll
  for (int b = 0; b < 8; ++b) {
    float keep = (p & 4) ? a[b + 8] : a[b];
    float send = (p & 4) ? a[b] : a[b + 8];
    t8[b] = keep + __shfl_xor(send, 4);
  }
  float t4[4];
#pragma unroll
  for (int b = 0; b < 4; ++b) {
    float keep = (p & 2) ? t8[b + 4] : t8[b];
    float send = (p & 2) ? t8[b] : t8[b + 4];
    t4[b] = keep + __shfl_xor(send, 2);
  }
  float t2[2];
#pragma unroll
  for (int b = 0; b < 2; ++b) {
    float keep = (p & 1) ? t4[b + 2] : t4[b];
    float send = (p & 1) ? t4[b] : t4[b + 2];
    t2[b] = keep + __shfl_xor(send, 1);
  }
  return make_float2(t2[0], t2[1]);
}

__global__ __launch_bounds__(256) void k_scores(const float4* __restrict__ keys4, const float4* __restrict__ q4,
                                                const int* __restrict__ vals, const float* __restrict__ age,
                                                float* __restrict__ outf, float* __restrict__ scores) {
  __shared__ float4 ql[512];        // 8 KB: query (16 rows x 128)
  __shared__ float tile[32 * 128];  // 16 KB: 32 key rows for aligned copy-out
  int tid = threadIdx.x;
  for (int i = tid; i < 512; i += 256) ql[i] = q4[i];
  // vals/age copy: one row per thread, coalesced 4-B stores
  int mc = blockIdx.x * 256 + tid;
  outf[OFF_VALS + mc] = (float)vals[mc];
  outf[OFF_AGE + mc] = age[mc] + 1.f;
  __syncthreads();

  int p = tid & 7, r = tid >> 3;               // 8 lanes per row, 32 rows per pass
  float2* sc2 = (float2*)scores;
  int m_base = blockIdx.x * 256;

#pragma unroll 1
  for (int t = 0; t < 8; ++t) {                // 8 passes x 32 rows = 256 rows/block
    int row = m_base + t * 32 + r;
    float4 kv[4];
#pragma unroll
    for (int u = 0; u < 4; ++u)
      kv[u] = keys4[(size_t)row * 32 + u * 8 + p];   // 8 full lines / instr

    float acc[16];
#pragma unroll
    for (int b = 0; b < 16; ++b) acc[b] = 0.f;
#pragma unroll
    for (int u = 0; u < 4; ++u) {
#pragma unroll
      for (int b = 0; b < 16; ++b) {
        float4 q = ql[b * 32 + u * 8 + p];     // whole-wave same addr: broadcast, free
        acc[b] += kv[u].x * q.x + kv[u].y * q.y + kv[u].z * q.z + kv[u].w * q.w;
      }
    }
    // lane p writes scores b=2p,2p+1: wave covers 512 contiguous bytes per store
    sc2[(size_t)row * 8 + p] = reduce_scatter8(acc, p);

    // stage key tile to LDS (row-major), then aligned linear copy-out
    float4* tl4 = (float4*)(tile + r * 128);
#pragma unroll
    for (int u = 0; u < 4; ++u) tl4[u * 8 + p] = kv[u];
    __syncthreads();
    {
      size_t S = (size_t)OFF_KEYS + ((size_t)m_base + (size_t)t * 32) * KD;
      float4* dst = (float4*)(outf + S + 2);   // (S+2)*4 is 16-B aligned
#pragma unroll 1
      for (int j = tid; j < 1023; j += 256) {
        float4 v = make_float4(tile[j * 4 + 2], tile[j * 4 + 3],
                               tile[j * 4 + 4], tile[j * 4 + 5]);
        dst[j] = v;
      }
      if (tid == 0) {
        *(float2*)(outf + S) = make_float2(tile[0], tile[1]);
        *(float2*)(outf + S + 4094) = make_float2(tile[4094], tile[4095]);
      }
    }
    __syncthreads();
  }
}

// ---------------- K5: per-row histogram of scores >= 0.0625 (bin = float hi-16 bits) ----------------
__global__ __launch_bounds__(256) void k_hist(const float* __restrict__ scores, u32* __restrict__ ghist) {
  __shared__ u32 h[16 * 640];
  int tid = threadIdx.x;
  for (int i = tid; i < 16 * 640; i += 256) h[i] = 0;
  __syncthreads();
  int m0 = blockIdx.x * 1024;
  for (int s = 0; s < 4; ++s) {
    int m = m0 + s * 256 + tid;
    const float4* sc = (const float4*)(scores + (size_t)m * 16);
#pragma unroll
    for (int g = 0; g < 4; ++g) {
      float4 v = sc[g];
      float fv[4] = {v.x, v.y, v.z, v.w};
#pragma unroll
      for (int c = 0; c < 4; ++c) {
        float f = fv[c];
        if (f >= 0.0625f) {
          u32 u = __float_as_uint(f);
          int bin = (int)(u >> 16) - 0x3D80;
          if (bin > 639) bin = 639;
          atomicAdd(&h[(g * 4 + c) * 640 + bin], 1u);
        }
      }
    }
  }
  __syncthreads();
  for (int i = tid; i < 16 * 640; i += 256) {
    u32 v = h[i];
    if (v) atomicAdd(&ghist[i], v);
  }
}

// ---------------- K6: per-row threshold value from histogram (wave suffix-scan) ----------------
__global__ void k_scan(const u32* __restrict__ ghist, float* __restrict__ thresh) {
  int b = blockIdx.x;
  int l = threadIdx.x;  // 64 lanes
  u32 carry = 0;
  for (int c = 0; c < 10; ++c) {
    int bin = 639 - (c * 64 + l);
    u32 v = (bin >= 0) ? ghist[b * 640 + bin] : 0u;
    u32 s = v;
    for (int o = 1; o < 64; o <<= 1) {
      u32 t = (u32)__shfl_up((int)s, o);
      if (l >= o) s += t;
    }
    u64 mask = __ballot(carry + s >= 256u);
    if (mask) {
      int first = __ffsll((long long)mask) - 1;
      if (l == first) thresh[b] = __uint_as_float(((u32)(bin + 0x3D80)) << 16);
      return;
    }
    carry += (u32)__shfl((int)s, 63);
  }
  if (l == 0) thresh[b] = __uint_as_float(((u32)0x3D80) << 16);  // T=0 fallback
}

// ---------------- K7: gather candidates >= threshold ----------------
__global__ __launch_bounds__(256) void k_gather(const float* __restrict__ scores, const float* __restrict__ thresh,
                                                int* __restrict__ cnt, int2* __restrict__ cand) {
  __shared__ float th[16];
  int tid = threadIdx.x;
  if (tid < 16) th[tid] = thresh[tid];
  __syncthreads();
  int m0 = blockIdx.x * 1024;
  for (int s = 0; s < 4; ++s) {
    int m = m0 + s * 256 + tid;
    const float4* sc = (const float4*)(scores + (size_t)m * 16);
#pragma unroll
    for (int g = 0; g < 4; ++g) {
      float4 v = sc[g];
      float fv[4] = {v.x, v.y, v.z, v.w};
#pragma unroll
      for (int c = 0; c < 4; ++c) {
        int b = g * 4 + c;
        float f = fv[c];
        if (f >= th[b]) {
          int p = atomicAdd(&cnt[b], 1);
          if (p < 2048) cand[b * 2048 + p] = make_int2(__float_as_int(f), m);
        }
      }
    }
  }
}

// ---------------- K8: per-row exact top-256 (bitonic), softmax, margin loss ----------------
__global__ __launch_bounds__(256) void k_topk(const int2* __restrict__ cand, const int* __restrict__ cnt,
                                              const int* __restrict__ vals, const int* __restrict__ ymax,
                                              float* __restrict__ outf, float* __restrict__ rowloss,
                                              int* __restrict__ yhatidx, int* __restrict__ result) {
  int b = blockIdx.x, tid = threadIdx.x;
  __shared__ u64 sk[2048];
  __shared__ float rb[256];
  __shared__ int sidx0;
  int nc = cnt[b];
  if (nc > 2048) nc = 2048;
  for (int i = tid; i < 2048; i += 256) {
    u64 key = 0;
    if (i < nc) {
      int2 c = cand[b * 2048 + i];
      key = ((u64)(u32)c.x << 32) | (u32)(~(u32)c.y);  // score desc, idx asc
    }
    sk[i] = key;
  }
  __syncthreads();
  for (int k2 = 2; k2 <= 2048; k2 <<= 1)
    for (int j2 = k2 >> 1; j2 > 0; j2 >>= 1) {
      for (int i = tid; i < 2048; i += 256) {
        int ix = i ^ j2;
        if (ix > i) {
          u64 x = sk[i], y = sk[ix];
          bool sw = ((i & k2) == 0) ? (x < y) : (x > y);  // descending
          if (sw) { sk[i] = y; sk[ix] = x; }
        }
      }
      __syncthreads();
    }
  int y = ymax[b];
  u64 kk = sk[tid];
  float c_ = __uint_as_float((u32)(kk >> 32));
  int id = (int)(~(u32)(kk & 0xFFFFFFFFull));
  id = min(max(id, 0), NM - 1);
  int vv = vals[id];
  int mk = (vv == y) ? 1 : 0;
  if (tid == 0) sidx0 = id;
  float mx = __uint_as_float((u32)(sk[0] >> 32));
  float e = expf(c_ - mx);
  rb[tid] = e; __syncthreads();
  for (int o = 128; o > 0; o >>= 1) { if (tid < o) rb[tid] += rb[tid + o]; __syncthreads(); }
  float esum = rb[0]; __syncthreads();
  outf[OFF_SM + b * 256 + tid] = e / esum;
  rb[tid] = c_ * (float)mk; __syncthreads();
  for (int o = 128; o > 0; o >>= 1) { if (tid < o) rb[tid] = fmaxf(rb[tid], rb[tid + o]); __syncthreads(); }
  float pmax = rb[0]; __syncthreads();
  rb[tid] = c_ * (float)(1 - mk); __syncthreads();
  for (int o = 128; o > 0; o >>= 1) { if (tid < o) rb[tid] = fmaxf(rb[tid], rb[tid + o]); __syncthreads(); }
  float nmax = rb[0]; __syncthreads();
  rb[tid] = (float)mk; __syncthreads();
  for (int o = 128; o > 0; o >>= 1) { if (tid < o) rb[tid] += rb[tid + o]; __syncthreads(); }
  float msum = rb[0];
  if (tid == 0) {
    float pos = (msum > 0.f) ? pmax : 0.f;
    rowloss[b] = fmaxf(nmax - pos + 0.1f, 0.f);
    int yh = vals[sidx0];
    yhatidx[b] = sidx0;
    result[b] = (yh == y) ? 1 : 0;
    outf[OFF_YHAT + b] = (float)yh;
  }
}

// ---------------- K9: correct-prediction key refresh (serial b, last-wins) + cls_loss ----------------
__global__ __launch_bounds__(128) void k_corr(const float* __restrict__ keys, const float* __restrict__ qws,
                                              const float* __restrict__ rowloss, const int* __restrict__ yhatidx,
                                              const int* __restrict__ result, float* __restrict__ outf) {
  int tid = threadIdx.x;
  __shared__ float partial[2];
  if (tid == 0) {
    float sum = 0.f;
    for (int b = 0; b < NB; ++b) sum += rowloss[b];
    outf[OFF_CLS] = sum * (1.f / 16.f);
  }
  for (int b = 0; b < NB; ++b) {
    if (result[b]) {
      int dest = yhatidx[b];
      float v = keys[(size_t)dest * KD + tid] + qws[b * KD + tid];
      float sq = v * v;
      for (int o = 32; o > 0; o >>= 1) sq += __shfl_down(sq, o);
      if ((tid & 63) == 0) partial[tid >> 6] = sq;
      __syncthreads();
      float nrm = sqrtf(partial[0] + partial[1]);
      outf[OFF_KEYS + (size_t)dest * KD + tid] = v / fmaxf(nrm, 1e-12f);
      if (tid == 0) outf[OFF_AGE + dest] = 0.f;
    }
    __syncthreads();
  }
}

__device__ __forceinline__ int age_bin(float an) {
  // deterministic (no-contract) binning, identical in hist and gather kernels
  float x = __fmul_rn(__fadd_rn(an, 8.f), 8192.f / 120.f);
  int bin = (int)x;
  return min(max(bin, 0), 8191);
}

// ---------------- K10a: histogram of age_noisy ----------------
__global__ __launch_bounds__(256) void k_hage(const float* __restrict__ oage, const float* __restrict__ noise,
                                              u32* __restrict__ hist) {
  __shared__ u32 h[8192];
  int tid = threadIdx.x;
  for (int i = tid; i < 8192; i += 256) h[i] = 0;
  __syncthreads();
  int m0 = blockIdx.x * 4096;
  for (int s = 0; s < 16; ++s) {
    int m = m0 + s * 256 + tid;
    float an = oage[m] + (noise[m] * 2.f - 1.f) * 8.f;
    atomicAdd(&h[age_bin(an)], 1u);
  }
  __syncthreads();
  for (int i = tid; i < 8192; i += 256) {
    u32 v = h[i];
    if (v) atomicAdd(&hist[i], v);
  }
}

// ---------------- K10b: threshold bin for top-16 (wave suffix-scan) ----------------
__global__ void k_scan_age(const u32* __restrict__ hist, int* __restrict__ T) {
  int l = threadIdx.x;  // 64 lanes
  u32 carry = 0;
  for (int c = 0; c < 128; ++c) {
    int bin = 8191 - (c * 64 + l);
    u32 v = hist[bin];
    u32 s = v;
    for (int o = 1; o < 64; o <<= 1) {
      u32 t = (u32)__shfl_up((int)s, o);
      if (l >= o) s += t;
    }
    u64 mask = __ballot(carry + s >= 16u);
    if (mask) {
      int first = __ffsll((long long)mask) - 1;
      if (l == first) *T = bin;
      return;
    }
    carry += (u32)__shfl((int)s, 63);
  }
  if (l == 0) *T = 0;
}

// ---------------- K10c: gather age candidates ----------------
__global__ __launch_bounds__(256) void k_gage(const float* __restrict__ oage, const float* __restrict__ noise,
                                              const int* __restrict__ T, int* __restrict__ cnt,
                                              int2* __restrict__ cand) {
  int tb = *T;
  int tid = threadIdx.x;
  int m0 = blockIdx.x * 1024;
  for (int s = 0; s < 4; ++s) {
    int m = m0 + s * 256 + tid;
    float an = oage[m] + (noise[m] * 2.f - 1.f) * 8.f;
    if (age_bin(an) >= tb) {
      int p = atomicAdd(cnt, 1);
      if (p < 4096) {
        u32 u = __float_as_uint(an);
        u = (u & 0x80000000u) ? ~u : (u | 0x80000000u);  // order-preserving flip
        cand[p] = make_int2((int)u, m);
      }
    }
  }
}

// ---------------- K11: oldest top-16, incorrect-prediction inserts ----------------
__global__ __launch_bounds__(256) void k_inc(const int* __restrict__ cnt, const int2* __restrict__ cand,
                                             const float* __restrict__ qws, const int* __restrict__ ymax,
                                             const int* __restrict__ result, float* __restrict__ outf) {
  __shared__ u64 sk[2048];
  __shared__ int oldest[16];
  __shared__ int dest[16];
  int tid = threadIdx.x;
  int nc = *cnt;
  if (nc > 2048) nc = 2048;
  for (int i = tid; i < 2048; i += 256) {
    u64 key = 0;
    if (i < nc) {
      int2 c = cand[i];
      key = ((u64)(u32)c.x << 32) | (u32)(~(u32)c.y);
    }
    sk[i] = key;
  }
  __syncthreads();
  for (int k2 = 2; k2 <= 2048; k2 <<= 1)
    for (int j2 = k2 >> 1; j2 > 0; j2 >>= 1) {
      for (int i = tid; i < 2048; i += 256) {
        int ix = i ^ j2;
        if (ix > i) {
          u64 x = sk[i], y = sk[ix];
          bool sw = ((i & k2) == 0) ? (x < y) : (x > y);
          if (sw) { sk[i] = y; sk[ix] = x; }
        }
      }
      __syncthreads();
    }
  if (tid < 16) {
    int id = (int)(~(u32)(sk[tid] & 0xFFFFFFFFull));
    oldest[tid] = min(max(id, 0), NM - 1);
  }
  __syncthreads();
  if (tid == 0) {
    int r = 0;
    for (int b = 0; b < NB; ++b) {
      if (!result[b]) { dest[b] = oldest[min(r, 15)]; r++; }
      else dest[b] = -1;
    }
  }
  __syncthreads();
  for (int b = 0; b < NB; ++b) {
    int d = dest[b];
    if (d >= 0) {
      if (tid < KD) outf[OFF_KEYS + (size_t)d * KD + tid] = qws[b * KD + tid];
      if (tid == 0) {
        outf[OFF_VALS + d] = (float)ymax[b];
        outf[OFF_AGE + d] = 0.f;
      }
    }
  }
}

extern "C" void kernel_launch(void* const* d_in, const int* in_sizes, int n_in,
                              void* d_out, int out_size, void* d_ws, size_t ws_size,
                              hipStream_t stream) {
  const float4* lp   = (const float4*)d_in[0];
  const float4* cls4 = (const float4*)d_in[1];
  const float4* lt   = (const float4*)d_in[2];
  const int* tgt     = (const int*)d_in[3];
  const float* keys  = (const float*)d_in[4];
  const int* vals    = (const int*)d_in[5];
  const float* age   = (const float*)d_in[6];
  const float* noise = (const float*)d_in[7];
  float* outf = (float*)d_out;
  char* ws = (char*)d_ws;

  hipMemsetAsync(ws, 0, WS_ZERO, stream);
  k_cls_sum<<<512, 256, 0, stream>>>(cls4, tgt, (float*)(ws + WS_SAMPLES));
  k_loc<<<1024, 256, 0, stream>>>(lp, lt, tgt, (float*)(ws + WS_NUMPOS),
                                  (int*)(ws + WS_YMAX), (float*)(ws + WS_LOCSUM));
  k_query<<<1, 128, 0, stream>>>((const float*)(ws + WS_SAMPLES), (const float*)(ws + WS_NUMPOS),
                                 (const int*)(ws + WS_YMAX), (const float*)(ws + WS_LOCSUM),
                                 (float*)(ws + WS_QUERY), outf);
  k_scores<<<2048, 256, 0, stream>>>((const float4*)keys, (const float4*)(ws + WS_QUERY),
                                     vals, age, outf, (float*)(ws + WS_SCORES));
  k_hist<<<512, 256, 0, stream>>>((const float*)(ws + WS_SCORES), (u32*)(ws + WS_HISTS));
  k_scan<<<16, 64, 0, stream>>>((const u32*)(ws + WS_HISTS), (float*)(ws + WS_THRESH));
  k_gather<<<512, 256, 0, stream>>>((const float*)(ws + WS_SCORES), (const float*)(ws + WS_THRESH),
                                    (int*)(ws + WS_CANDCNT), (int2*)(ws + WS_CAND));
  k_topk<<<16, 256, 0, stream>>>((const int2*)(ws + WS_CAND), (const int*)(ws + WS_CANDCNT),
                                 vals, (const int*)(ws + WS_YMAX), outf, (float*)(ws + WS_ROWLOSS),
                                 (int*)(ws + WS_YHATIDX), (int*)(ws + WS_RESULT));
  k_corr<<<1, 128, 0, stream>>>(keys, (const float*)(ws + WS_QUERY), (const float*)(ws + WS_ROWLOSS),
                                (const int*)(ws + WS_YHATIDX), (const int*)(ws + WS_RESULT), outf);
  k_hage<<<128, 256, 0, stream>>>(outf + OFF_AGE, noise, (u32*)(ws + WS_HISTAGE));
  k_scan_age<<<1, 64, 0, stream>>>((const u32*)(ws + WS_HISTAGE), (int*)(ws + WS_AGETH));
  k_gage<<<512, 256, 0, stream>>>(outf + OFF_AGE, noise, (const int*)(ws + WS_AGETH),
                                  (int*)(ws + WS_AGECNT), (int2*)(ws + WS_AGECAND));
  k_inc<<<1, 256, 0, stream>>>((const int*)(ws + WS_AGECNT), (const int2*)(ws + WS_AGECAND),
                               (const float*)(ws + WS_QUERY), (const int*)(ws + WS_YMAX),
                               (const int*)(ws + WS_RESULT), outf);
}

// Round 3
// 791.389 us; speedup vs baseline: 1.5998x; 1.1083x over previous
//
#include <hip/hip_runtime.h>
#include <stdint.h>

typedef unsigned int u32;
typedef unsigned long long u64;

#define NB 16
#define NA 16384
#define KD 128
#define NM 524288

// output offsets (floats)
#define OFF_Y    0
#define OFF_YHAT 16
#define OFF_SM   32
#define OFF_CLS  4128
#define OFF_LOC  4129
#define OFF_Q    4130
#define OFF_KEYS 6178
#define OFF_VALS 67115042
#define OFF_AGE  67639330

// ws offsets (bytes)
#define WS_SAMPLES 0        // 16*128 f32
#define WS_NUMPOS  8192     // 16 f32
#define WS_YMAX    8256     // 16 i32
#define WS_LOCSUM  8320     // 1 f32
#define WS_QUERY   8384     // 16*128 f32
#define WS_ROWLOSS 16576    // 16 f32
#define WS_YHATIDX 16640    // 16 i32
#define WS_RESULT  16768    // 16 i32
#define WS_HISTS   16832    // 16*640 u32
#define WS_THRESH  57792    // 16 f32
#define WS_CANDCNT 57856    // 16 i32
#define WS_HISTAGE 57920    // 8192 u32
#define WS_AGETH   90688    // 1 i32
#define WS_AGECNT  90692    // 1 i32
#define WS_AGECAND 90816    // 4096 int2
#define WS_CAND    123584   // 16*2048 int2
#define WS_SCORES  385728   // NM*16 f32 (transposed: scores[m*16+b])
#define WS_ZERO0   8384     // memset only [0, 8384); k_query zeroes [16832, 90696)

// ---------------- K1: cls_sum role (blk<512) | loc role (blk>=512) ----------------
__global__ __launch_bounds__(256) void k_front(const float4* __restrict__ cls4,
                                               const int* __restrict__ tgt,
                                               const float4* __restrict__ lp,
                                               const float4* __restrict__ lt,
                                               float* __restrict__ samples,
                                               float* __restrict__ numpos,
                                               int* __restrict__ ymax,
                                               float* __restrict__ locsum) {
  int blk = blockIdx.x;
  int tid = threadIdx.x;
  if (blk < 512) {
    // ---- cls_sum: samples[b][k] = sum_a pos * cls_preds ----
    int b = blk >> 5, chunk = blk & 31;          // 32 chunks of 512 anchors
    int kg = tid & 31, sub = tid >> 5;           // kg: float4 group (128 k), sub: 0..7
    float4 acc = make_float4(0.f, 0.f, 0.f, 0.f);
    int a0 = chunk * 512;
    for (int a = a0 + sub; a < a0 + 512; a += 8) {
      int t = tgt[b * NA + a];
      if (t > 0) {
        float4 v = cls4[((size_t)(b * NA + a)) * 32 + kg];
        acc.x += v.x; acc.y += v.y; acc.z += v.z; acc.w += v.w;
      }
    }
    __shared__ float4 red[256];
    red[tid] = acc;
    __syncthreads();
    if (tid < 32) {
      float4 s = red[tid];
      for (int r = 1; r < 8; ++r) {
        float4 v = red[r * 32 + tid];
        s.x += v.x; s.y += v.y; s.z += v.z; s.w += v.w;
      }
      atomicAdd(&samples[b * KD + kg * 4 + 0], s.x);
      atomicAdd(&samples[b * KD + kg * 4 + 1], s.y);
      atomicAdd(&samples[b * KD + kg * 4 + 2], s.z);
      atomicAdd(&samples[b * KD + kg * 4 + 3], s.w);
    }
  } else {
    // ---- loc: num_pos, loc_loss partial, y = max target ----
    int i = (blk - 512) * 256 + tid;
    int b = i >> 14;
    int t = tgt[i];
    float cnt = (t > 0) ? 1.f : 0.f;
    float sl = 0.f;
    if (t > 0) {
      float4 p = lp[i], q = lt[i];
      float d0 = p.x - q.x, d1 = p.y - q.y, d2 = p.z - q.z, d3 = p.w - q.w;
      float a0 = fabsf(d0), a1 = fabsf(d1), a2 = fabsf(d2), a3 = fabsf(d3);
      sl = ((a0 < 1.f) ? 0.5f * d0 * d0 : a0 - 0.5f)
         + ((a1 < 1.f) ? 0.5f * d1 * d1 : a1 - 0.5f)
         + ((a2 < 1.f) ? 0.5f * d2 * d2 : a2 - 0.5f)
         + ((a3 < 1.f) ? 0.5f * d3 * d3 : a3 - 0.5f);
    }
    for (int o = 32; o > 0; o >>= 1) {
      sl += __shfl_down(sl, o);
      cnt += __shfl_down(cnt, o);
      t = max(t, __shfl_down(t, o));
    }
    __shared__ float s_sl[4], s_cnt[4];
    __shared__ int s_t[4];
    int lane = tid & 63, w = tid >> 6;
    if (lane == 0) { s_sl[w] = sl; s_cnt[w] = cnt; s_t[w] = t; }
    __syncthreads();
    if (tid == 0) {
      float SL = s_sl[0] + s_sl[1] + s_sl[2] + s_sl[3];
      float CN = s_cnt[0] + s_cnt[1] + s_cnt[2] + s_cnt[3];
      int T = max(max(s_t[0], s_t[1]), max(s_t[2], s_t[3]));
      atomicAdd(&numpos[b], CN);
      atomicAdd(locsum, SL);
      atomicMax(&ymax[b], T);
    }
  }
}

// ---------------- K3: query = l2norm(samples/num_pos); y, loc_loss out; zero ws ----------------
// 16 blocks (one per b), 256 threads; threads also zero the hist-family ws regions.
__global__ __launch_bounds__(256) void k_query(const float* __restrict__ samples, const float* __restrict__ numpos,
                                               const int* __restrict__ ymax, const float* __restrict__ locsum,
                                               float* __restrict__ qws, float* __restrict__ outf,
                                               u32* __restrict__ zbase) {
  int tid = threadIdx.x, b = blockIdx.x;
  __shared__ float part[2];
  float v = 0.f;
  if (tid < 128) v = samples[b * KD + tid] / numpos[b];
  float sq = v * v;
  for (int o = 32; o > 0; o >>= 1) sq += __shfl_down(sq, o);
  if (tid < 128 && (tid & 63) == 0) part[tid >> 6] = sq;
  __syncthreads();
  if (tid < 128) {
    float nrm = sqrtf(part[0] + part[1]);
    float q = v / fmaxf(nrm, 1e-12f);
    qws[b * KD + tid] = q;
    outf[OFF_Q + b * KD + tid] = q;
  }
  // zero [WS_HISTS, WS_AGECNT+4) = 73864 B = 18466 u32 across 16 blocks
  for (int i = b * 256 + tid; i < 18466; i += 4096) zbase[i] = 0;
  if (b == 0) {
    if (tid < 16) outf[OFF_Y + tid] = (float)ymax[tid];
    if (tid == 0) {
      float tot = 0.f;
      for (int j = 0; j < NB; ++j) tot += numpos[j];
      outf[OFF_LOC] = locsum[0] / tot;
    }
  }
}

// ---------------- K4: scores = query @ keys.T ; copy keys/values/age to out ----------------
// 8 lanes per key row (lane p owns float4s {p, p+8, p+16, p+24}) -> every global LOAD
// instruction covers 8 full 128-B lines. 1 row/thread keeps VGPR ~70 (occupancy).
// Copy-out goes through a 16-KB LDS tile so stores are 16-B-aligned float4 on the
// shifted grid (OFF_KEYS+2): each store instruction = 1024 contiguous fully-dirty bytes.
__device__ __forceinline__ float2 reduce_scatter8(const float* a, int p) {
  float t8[8];
#pragma unroll
  for (int b = 0; b < 8; ++b) {
    float keep = (p & 4) ? a[b + 8] : a[b];
    float send = (p & 4) ? a[b] : a[b + 8];
    t8[b] = keep + __shfl_xor(send, 4);
  }
  float t4[4];
#pragma unroll
  for (int b = 0; b < 4; ++b) {
    float keep = (p & 2) ? t8[b + 4] : t8[b];
    float send = (p & 2) ? t8[b] : t8[b + 4];
    t4[b] = keep + __shfl_xor(send, 2);
  }
  float t2[2];
#pragma unroll
  for (int b = 0; b < 2; ++b) {
    float keep = (p & 1) ? t4[b + 2] : t4[b];
    float send = (p & 1) ? t4[b] : t4[b + 2];
    t2[b] = keep + __shfl_xor(send, 1);
  }
  return make_float2(t2[0], t2[1]);
}

__global__ __launch_bounds__(256) void k_scores(const float4* __restrict__ keys4, const float4* __restrict__ q4,
                                                const int* __restrict__ vals, const float* __restrict__ age,
                                                float* __restrict__ outf, float* __restrict__ scores) {
  __shared__ float4 ql[512];        // 8 KB: query (16 rows x 128)
  __shared__ float tile[32 * 128];  // 16 KB: 32 key rows for aligned copy-out
  int tid = threadIdx.x;
  for (int i = tid; i < 512; i += 256) ql[i] = q4[i];
  int mc = blockIdx.x * 256 + tid;
  outf[OFF_VALS + mc] = (float)vals[mc];
  outf[OFF_AGE + mc] = age[mc] + 1.f;
  __syncthreads();

  int p = tid & 7, r = tid >> 3;               // 8 lanes per row, 32 rows per pass
  float2* sc2 = (float2*)scores;
  int m_base = blockIdx.x * 256;

#pragma unroll 1
  for (int t = 0; t < 8; ++t) {                // 8 passes x 32 rows = 256 rows/block
    int row = m_base + t * 32 + r;
    float4 kv[4];
#pragma unroll
    for (int u = 0; u < 4; ++u)
      kv[u] = keys4[(size_t)row * 32 + u * 8 + p];   // 8 full lines / instr

    float acc[16];
#pragma unroll
    for (int b = 0; b < 16; ++b) acc[b] = 0.f;
#pragma unroll
    for (int u = 0; u < 4; ++u) {
#pragma unroll
      for (int b = 0; b < 16; ++b) {
        float4 q = ql[b * 32 + u * 8 + p];
        acc[b] += kv[u].x * q.x + kv[u].y * q.y + kv[u].z * q.z + kv[u].w * q.w;
      }
    }
    sc2[(size_t)row * 8 + p] = reduce_scatter8(acc, p);

    float4* tl4 = (float4*)(tile + r * 128);
#pragma unroll
    for (int u = 0; u < 4; ++u) tl4[u * 8 + p] = kv[u];
    __syncthreads();
    {
      size_t S = (size_t)OFF_KEYS + ((size_t)m_base + (size_t)t * 32) * KD;
      float4* dst = (float4*)(outf + S + 2);   // (S+2)*4 is 16-B aligned
#pragma unroll 1
      for (int j = tid; j < 1023; j += 256) {
        float4 v = make_float4(tile[j * 4 + 2], tile[j * 4 + 3],
                               tile[j * 4 + 4], tile[j * 4 + 5]);
        dst[j] = v;
      }
      if (tid == 0) {
        *(float2*)(outf + S) = make_float2(tile[0], tile[1]);
        *(float2*)(outf + S + 4094) = make_float2(tile[4094], tile[4095]);
      }
    }
    __syncthreads();
  }
}

__device__ __forceinline__ int age_bin(float an) {
  float x = __fmul_rn(__fadd_rn(an, 8.f), 8192.f / 120.f);
  int bin = (int)x;
  return min(max(bin, 0), 8191);
}

// ---------------- K5: hist role (blk<512) | hage role (blk>=512) ----------------
__global__ __launch_bounds__(256) void k_histx(const float* __restrict__ scores, u32* __restrict__ ghist,
                                               const float* __restrict__ oage, const float* __restrict__ noise,
                                               u32* __restrict__ ahist) {
  __shared__ u32 h[16 * 640];
  int blk = blockIdx.x;
  int tid = threadIdx.x;
  if (blk < 512) {
    for (int i = tid; i < 16 * 640; i += 256) h[i] = 0;
    __syncthreads();
    int m0 = blk * 1024;
    for (int s = 0; s < 4; ++s) {
      int m = m0 + s * 256 + tid;
      const float4* sc = (const float4*)(scores + (size_t)m * 16);
#pragma unroll
      for (int g = 0; g < 4; ++g) {
        float4 v = sc[g];
        float fv[4] = {v.x, v.y, v.z, v.w};
#pragma unroll
        for (int c = 0; c < 4; ++c) {
          float f = fv[c];
          if (f >= 0.0625f) {
            u32 u = __float_as_uint(f);
            int bin = (int)(u >> 16) - 0x3D80;
            if (bin > 639) bin = 639;
            atomicAdd(&h[(g * 4 + c) * 640 + bin], 1u);
          }
        }
      }
    }
    __syncthreads();
    for (int i = tid; i < 16 * 640; i += 256) {
      u32 v = h[i];
      if (v) atomicAdd(&ghist[i], v);
    }
  } else {
    for (int i = tid; i < 8192; i += 256) h[i] = 0;
    __syncthreads();
    int m0 = (blk - 512) * 4096;
    for (int s = 0; s < 16; ++s) {
      int m = m0 + s * 256 + tid;
      float an = oage[m] + (noise[m] * 2.f - 1.f) * 8.f;
      atomicAdd(&h[age_bin(an)], 1u);
    }
    __syncthreads();
    for (int i = tid; i < 8192; i += 256) {
      u32 v = h[i];
      if (v) atomicAdd(&ahist[i], v);
    }
  }
}

// ---------------- K6: scan role (blk<16) | scan_age role (blk==16) ----------------
__global__ void k_scanx(const u32* __restrict__ ghist, float* __restrict__ thresh,
                        const u32* __restrict__ ahist, int* __restrict__ T) {
  int blk = blockIdx.x;
  int l = threadIdx.x;  // 64 lanes
  if (blk < 16) {
    u32 carry = 0;
    for (int c = 0; c < 10; ++c) {
      int bin = 639 - (c * 64 + l);
      u32 v = (bin >= 0) ? ghist[blk * 640 + bin] : 0u;
      u32 s = v;
      for (int o = 1; o < 64; o <<= 1) {
        u32 t = (u32)__shfl_up((int)s, o);
        if (l >= o) s += t;
      }
      u64 mask = __ballot(carry + s >= 256u);
      if (mask) {
        int first = __ffsll((long long)mask) - 1;
        if (l == first) thresh[blk] = __uint_as_float(((u32)(bin + 0x3D80)) << 16);
        return;
      }
      carry += (u32)__shfl((int)s, 63);
    }
    if (l == 0) thresh[blk] = __uint_as_float(((u32)0x3D80) << 16);
  } else {
    u32 carry = 0;
    for (int c = 0; c < 128; ++c) {
      int bin = 8191 - (c * 64 + l);
      u32 v = ahist[bin];
      u32 s = v;
      for (int o = 1; o < 64; o <<= 1) {
        u32 t = (u32)__shfl_up((int)s, o);
        if (l >= o) s += t;
      }
      u64 mask = __ballot(carry + s >= 16u);
      if (mask) {
        int first = __ffsll((long long)mask) - 1;
        if (l == first) *T = bin;
        return;
      }
      carry += (u32)__shfl((int)s, 63);
    }
    if (l == 0) *T = 0;
  }
}

// ---------------- K7: gather role (blk<512) | gage role (blk>=512) ----------------
__global__ __launch_bounds__(256) void k_gatherx(const float* __restrict__ scores, const float* __restrict__ thresh,
                                                 int* __restrict__ cnt, int2* __restrict__ cand,
                                                 const float* __restrict__ oage, const float* __restrict__ noise,
                                                 const int* __restrict__ T, int* __restrict__ acnt,
                                                 int2* __restrict__ acand) {
  int blk = blockIdx.x;
  int tid = threadIdx.x;
  if (blk < 512) {
    __shared__ float th[16];
    if (tid < 16) th[tid] = thresh[tid];
    __syncthreads();
    int m0 = blk * 1024;
    for (int s = 0; s < 4; ++s) {
      int m = m0 + s * 256 + tid;
      const float4* sc = (const float4*)(scores + (size_t)m * 16);
#pragma unroll
      for (int g = 0; g < 4; ++g) {
        float4 v = sc[g];
        float fv[4] = {v.x, v.y, v.z, v.w};
#pragma unroll
        for (int c = 0; c < 4; ++c) {
          int b = g * 4 + c;
          float f = fv[c];
          if (f >= th[b]) {
            int p = atomicAdd(&cnt[b], 1);
            if (p < 2048) cand[b * 2048 + p] = make_int2(__float_as_int(f), m);
          }
        }
      }
    }
  } else {
    int tb = *T;
    int m0 = (blk - 512) * 1024;
    for (int s = 0; s < 4; ++s) {
      int m = m0 + s * 256 + tid;
      float an = oage[m] + (noise[m] * 2.f - 1.f) * 8.f;
      if (age_bin(an) >= tb) {
        int p = atomicAdd(acnt, 1);
        if (p < 4096) {
          u32 u = __float_as_uint(an);
          u = (u & 0x80000000u) ? ~u : (u | 0x80000000u);  // order-preserving flip
          acand[p] = make_int2((int)u, m);
        }
      }
    }
  }
}

// ---------------- K8: per-row exact top-256 (bitonic), softmax, margin loss ----------------
__global__ __launch_bounds__(256) void k_topk(const int2* __restrict__ cand, const int* __restrict__ cnt,
                                              const int* __restrict__ vals, const int* __restrict__ ymax,
                                              float* __restrict__ outf, float* __restrict__ rowloss,
                                              int* __restrict__ yhatidx, int* __restrict__ result) {
  int b = blockIdx.x, tid = threadIdx.x;
  __shared__ u64 sk[2048];
  __shared__ float rb[256];
  __shared__ int sidx0;
  int nc = cnt[b];
  if (nc > 2048) nc = 2048;
  for (int i = tid; i < 2048; i += 256) {
    u64 key = 0;
    if (i < nc) {
      int2 c = cand[b * 2048 + i];
      key = ((u64)(u32)c.x << 32) | (u32)(~(u32)c.y);  // score desc, idx asc
    }
    sk[i] = key;
  }
  __syncthreads();
  for (int k2 = 2; k2 <= 2048; k2 <<= 1)
    for (int j2 = k2 >> 1; j2 > 0; j2 >>= 1) {
      for (int i = tid; i < 2048; i += 256) {
        int ix = i ^ j2;
        if (ix > i) {
          u64 x = sk[i], y = sk[ix];
          bool sw = ((i & k2) == 0) ? (x < y) : (x > y);  // descending
          if (sw) { sk[i] = y; sk[ix] = x; }
        }
      }
      __syncthreads();
    }
  int y = ymax[b];
  u64 kk = sk[tid];
  float c_ = __uint_as_float((u32)(kk >> 32));
  int id = (int)(~(u32)(kk & 0xFFFFFFFFull));
  id = min(max(id, 0), NM - 1);
  int vv = vals[id];
  int mk = (vv == y) ? 1 : 0;
  if (tid == 0) sidx0 = id;
  float mx = __uint_as_float((u32)(sk[0] >> 32));
  float e = expf(c_ - mx);
  rb[tid] = e; __syncthreads();
  for (int o = 128; o > 0; o >>= 1) { if (tid < o) rb[tid] += rb[tid + o]; __syncthreads(); }
  float esum = rb[0]; __syncthreads();
  outf[OFF_SM + b * 256 + tid] = e / esum;
  rb[tid] = c_ * (float)mk; __syncthreads();
  for (int o = 128; o > 0; o >>= 1) { if (tid < o) rb[tid] = fmaxf(rb[tid], rb[tid + o]); __syncthreads(); }
  float pmax = rb[0]; __syncthreads();
  rb[tid] = c_ * (float)(1 - mk); __syncthreads();
  for (int o = 128; o > 0; o >>= 1) { if (tid < o) rb[tid] = fmaxf(rb[tid], rb[tid + o]); __syncthreads(); }
  float nmax = rb[0]; __syncthreads();
  rb[tid] = (float)mk; __syncthreads();
  for (int o = 128; o > 0; o >>= 1) { if (tid < o) rb[tid] += rb[tid + o]; __syncthreads(); }
  float msum = rb[0];
  if (tid == 0) {
    float pos = (msum > 0.f) ? pmax : 0.f;
    rowloss[b] = fmaxf(nmax - pos + 0.1f, 0.f);
    int yh = vals[sidx0];
    yhatidx[b] = sidx0;
    result[b] = (yh == y) ? 1 : 0;
    outf[OFF_YHAT + b] = (float)yh;
  }
}

// ---------------- K9: merged update kernel (17 blocks, 256 threads) ----------------
// All blocks redundantly compute the oldest-16 (successive argmax, identical u64
// ordering to the old bitonic) and the inc-dest mapping. Blocks 0..15: corr role for
// b = blk with last-wins winner filter + "inc overwrites corr" filter (bitwise-identical
// final state to the old serial corr -> inc sequence). Block 16: inc writes + cls_loss.
__global__ __launch_bounds__(256) void k_upd(const int* __restrict__ acnt, const int2* __restrict__ acand,
                                             const float* __restrict__ keys, const float* __restrict__ qws,
                                             const float* __restrict__ rowloss, const int* __restrict__ yhatidx,
                                             const int* __restrict__ result, const int* __restrict__ ymax,
                                             float* __restrict__ outf) {
  int tid = threadIdx.x;
  int blk = blockIdx.x;
  __shared__ int s_res[16], s_yhi[16], s_dinc[16], s_oldest[16];
  __shared__ u64 s_max[4];
  __shared__ u64 s_win;
  __shared__ float part[4];
  if (tid < 16) { s_res[tid] = result[tid]; s_yhi[tid] = yhatidx[tid]; }

  // load candidate keys into registers (8 per thread)
  int nc = *acnt;
  if (nc > 2048) nc = 2048;
  u64 k[8];
#pragma unroll
  for (int s = 0; s < 8; ++s) {
    int i = tid + s * 256;
    u64 key = 0;
    if (i < nc) {
      int2 c = acand[i];
      key = ((u64)(u32)c.x << 32) | (u32)(~(u32)c.y);  // age desc, idx asc
    }
    k[s] = key;
  }
  int lane = tid & 63, wv = tid >> 6;
  for (int r = 0; r < 16; ++r) {
    u64 mx = k[0];
#pragma unroll
    for (int s = 1; s < 8; ++s) mx = (k[s] > mx) ? k[s] : mx;
    for (int o = 32; o > 0; o >>= 1) {
      u64 other = __shfl_down(mx, o);
      mx = (other > mx) ? other : mx;
    }
    if (lane == 0) s_max[wv] = mx;
    __syncthreads();
    if (tid == 0) {
      u64 w = s_max[0];
      for (int i = 1; i < 4; ++i) w = (s_max[i] > w) ? s_max[i] : w;
      s_win = w;
      int id = (int)(~(u32)(w & 0xFFFFFFFFull));
      s_oldest[r] = min(max(id, 0), NM - 1);
    }
    __syncthreads();
    u64 w = s_win;
#pragma unroll
    for (int s = 0; s < 8; ++s) if (k[s] == w) k[s] = 0;
  }
  __syncthreads();
  if (tid == 0) {
    int r = 0;
    for (int b = 0; b < NB; ++b) {
      if (!s_res[b]) { s_dinc[b] = s_oldest[min(r, 15)]; r++; }
      else s_dinc[b] = -1;
    }
  }
  __syncthreads();

  // corr role (blocks 0..15), scaffold executed by all blocks (sync-safe)
  int b = (blk < 16) ? blk : 0;
  int dest = s_yhi[b];
  bool active = (blk < 16) && s_res[b];
  if (active) {
    for (int bp = b + 1; bp < NB; ++bp)
      if (s_res[bp] && s_yhi[bp] == dest) active = false;   // last-wins among corr
    for (int bp = 0; bp < NB; ++bp)
      if (s_dinc[bp] == dest) active = false;               // inc overwrites corr
  }
  float v = 0.f;
  if (active && tid < 128) v = keys[(size_t)dest * KD + tid] + qws[b * KD + tid];
  float sq = v * v;
  for (int o = 32; o > 0; o >>= 1) sq += __shfl_down(sq, o);
  if ((tid & 63) == 0) part[wv] = sq;
  __syncthreads();
  if (active && tid < 128) {
    float nrm = sqrtf(part[0] + part[1]);
    outf[OFF_KEYS + (size_t)dest * KD + tid] = v / fmaxf(nrm, 1e-12f);
  }
  if (active && tid == 0) outf[OFF_AGE + dest] = 0.f;

  // inc role (block 16) + cls_loss
  if (blk == 16) {
    for (int bb = 0; bb < NB; ++bb) {
      int d = s_dinc[bb];
      if (d >= 0) {
        if (tid < KD) outf[OFF_KEYS + (size_t)d * KD + tid] = qws[bb * KD + tid];
        if (tid == 0) {
          outf[OFF_VALS + d] = (float)ymax[bb];
          outf[OFF_AGE + d] = 0.f;
        }
      }
    }
    if (tid == 0) {
      float sum = 0.f;
      for (int bb = 0; bb < NB; ++bb) sum += rowloss[bb];
      outf[OFF_CLS] = sum * (1.f / 16.f);
    }
  }
}

extern "C" void kernel_launch(void* const* d_in, const int* in_sizes, int n_in,
                              void* d_out, int out_size, void* d_ws, size_t ws_size,
                              hipStream_t stream) {
  const float4* lp   = (const float4*)d_in[0];
  const float4* cls4 = (const float4*)d_in[1];
  const float4* lt   = (const float4*)d_in[2];
  const int* tgt     = (const int*)d_in[3];
  const float* keys  = (const float*)d_in[4];
  const int* vals    = (const int*)d_in[5];
  const float* age   = (const float*)d_in[6];
  const float* noise = (const float*)d_in[7];
  float* outf = (float*)d_out;
  char* ws = (char*)d_ws;

  hipMemsetAsync(ws, 0, WS_ZERO0, stream);
  k_front<<<1536, 256, 0, stream>>>(cls4, tgt, lp, lt, (float*)(ws + WS_SAMPLES),
                                    (float*)(ws + WS_NUMPOS), (int*)(ws + WS_YMAX),
                                    (float*)(ws + WS_LOCSUM));
  k_query<<<16, 256, 0, stream>>>((const float*)(ws + WS_SAMPLES), (const float*)(ws + WS_NUMPOS),
                                  (const int*)(ws + WS_YMAX), (const float*)(ws + WS_LOCSUM),
                                  (float*)(ws + WS_QUERY), outf, (u32*)(ws + WS_HISTS));
  k_scores<<<2048, 256, 0, stream>>>((const float4*)keys, (const float4*)(ws + WS_QUERY),
                                     vals, age, outf, (float*)(ws + WS_SCORES));
  k_histx<<<640, 256, 0, stream>>>((const float*)(ws + WS_SCORES), (u32*)(ws + WS_HISTS),
                                   outf + OFF_AGE, noise, (u32*)(ws + WS_HISTAGE));
  k_scanx<<<17, 64, 0, stream>>>((const u32*)(ws + WS_HISTS), (float*)(ws + WS_THRESH),
                                 (const u32*)(ws + WS_HISTAGE), (int*)(ws + WS_AGETH));
  k_gatherx<<<1024, 256, 0, stream>>>((const float*)(ws + WS_SCORES), (const float*)(ws + WS_THRESH),
                                      (int*)(ws + WS_CANDCNT), (int2*)(ws + WS_CAND),
                                      outf + OFF_AGE, noise, (const int*)(ws + WS_AGETH),
                                      (int*)(ws + WS_AGECNT), (int2*)(ws + WS_AGECAND));
  k_topk<<<16, 256, 0, stream>>>((const int2*)(ws + WS_CAND), (const int*)(ws + WS_CANDCNT),
                                 vals, (const int*)(ws + WS_YMAX), outf, (float*)(ws + WS_ROWLOSS),
                                 (int*)(ws + WS_YHATIDX), (int*)(ws + WS_RESULT));
  k_upd<<<17, 256, 0, stream>>>((const int*)(ws + WS_AGECNT), (const int2*)(ws + WS_AGECAND),
                                keys, (const float*)(ws + WS_QUERY), (const float*)(ws + WS_ROWLOSS),
                                (const int*)(ws + WS_YHATIDX), (const int*)(ws + WS_RESULT),
                                (const int*)(ws + WS_YMAX), outf);
}